// Round 12
// baseline (104.384 us; speedup 1.0000x reference)
//
#include <hip/hip_runtime.h>
#include <hip/hip_bf16.h>
#include <hip/hip_cooperative_groups.h>

namespace cg = cooperative_groups;

// b=8, H=8, n=1024, d=32, fp32 in, scalar MSE loss out.
// Per pair p: Qt[d][n] = f_s[p*32768 + d*1024 + n]. sim = QK^T (unscaled),
// softmax over j, out = PV, loss = mean((out - f_t)^2).
//
// Block = 512 thr (8 waves), 32 q-rows/wave. Grid = 256 (1/CU, XCD swizzle).
// R9-verified staging/layouts + 32x32x16 MFMA loop (best: 27.5us). NEW:
// single COOPERATIVE launch -- no memset dispatch, no atomicAdd. Blocks
// write partials to d_ws[bid], grid.sync(), block 0 reduces and WRITES out.

typedef __attribute__((ext_vector_type(4))) float f32x4;
typedef __attribute__((ext_vector_type(16))) float f32x16;
typedef __attribute__((ext_vector_type(8))) short bf16x8;
typedef __attribute__((ext_vector_type(4))) unsigned u32x4;

#define KOFF 0         // 64 subtiles x 1KB, R5 chunk layout (16 rows each)
#define VOFF 65536     // 16 tiles x [32 d][64 j] bf16, XOR-swizzled rows
#define QOFF 131072    // 8 waves x 2KB (two 16-row subtiles, R5 chunk layout)
#define REDX 40960     // block reduction scratch (K region, post-barrier)

__device__ __forceinline__ unsigned cvtpk(float a, float b) {
    unsigned r;  // r.lo = bf16(a), r.hi = bf16(b), RNE
    asm("v_cvt_pk_bf16_f32 %0, %1, %2" : "=v"(r) : "v"(a), "v"(b));
    return r;
}
#define SWAP32(a, b) asm("v_permlane32_swap_b32 %0, %1" : "+v"(a), "+v"(b))

__device__ __forceinline__ float expv(float x) {
    float r;  // 2^x, native trans op
    asm("v_exp_f32 %0, %1" : "=v"(r) : "v"(x));
    return r;
}

__global__ __launch_bounds__(512, 2)
void attn_mse_kernel(const float* __restrict__ fs, const float* __restrict__ ft,
                     float* __restrict__ out, float* __restrict__ ws)
{
    __shared__ __align__(16) unsigned char smem[147456];

    const int tid  = threadIdx.x;
    const int lane = tid & 63;
    const int w    = tid >> 6;     // wave 0..7
    const int g    = lane >> 4;    // staging role 0..3
    const int c    = lane & 15;    // staging role 0..15
    const int il   = lane & 31;    // MFMA M/N lane index
    const int hi   = lane >> 5;    // MFMA k-half

    // XCD swizzle: 8 pairs x 4 q-blocks per XCD (bid%8) -> 2MB L2 set.
    const int bid  = blockIdx.x;
    const int pair = (bid & 7) * 8 + ((bid >> 3) & 7);
    const int q0   = (bid >> 6) * 256;

    const float* qb = fs + (size_t)pair * 32768;  // Q and V source
    const float* kb = ft + (size_t)pair * 32768;  // K source + loss target

    // R5 chunk-staging lane roles: word(dp, j) = p*64 + 16*(j>>2) + 4*((j&3)^p) + g
    // where dp = 4p+g (d-pair). (verified R5-R9)
    const int p_ = c >> 2, jq = c & 3;
    const int dp = 4 * p_ + g;
    const int w0 = p_ * 64 + 16 * jq + 4 * (0 ^ p_) + g;
    const int w1 = p_ * 64 + 16 * jq + 4 * (1 ^ p_) + g;
    const int w2 = p_ * 64 + 16 * jq + 4 * (2 ^ p_) + g;
    const int w3 = p_ * 64 + 16 * jq + 4 * (3 ^ p_) + g;

    // ---- stage Q (2 x 16-row subtiles per wave, pre-scaled by log2 e)
    {
        const float sc = 1.44269504f;
        #pragma unroll
        for (int st = 0; st < 2; ++st) {
            const float* r0 = qb + (size_t)(2 * dp) * 1024 + (q0 + w * 32 + st * 16) + 4 * jq;
            const float4 a = *(const float4*)(r0);
            const float4 b = *(const float4*)(r0 + 1024);
            unsigned* dst = (unsigned*)(smem + QOFF + w * 2048 + st * 1024);
            dst[w0] = cvtpk(a.x * sc, b.x * sc);
            dst[w1] = cvtpk(a.y * sc, b.y * sc);
            dst[w2] = cvtpk(a.z * sc, b.z * sc);
            dst[w3] = cvtpk(a.w * sc, b.w * sc);
        }
    }
    // 32-row fragment read from R5 layout: row il, chunk b:
    // byte = (il>>4)<<10 | b<<8 | ((il>>2)&3)<<6 | ((il&3)^b)<<4
    const unsigned qsel = ((unsigned)(il >> 4) << 10) | (((unsigned)(il >> 2) & 3) << 6);
    const unsigned char* qbase = smem + QOFF + w * 2048 + qsel;
    const bf16x8 qfa = *(const bf16x8*)(qbase + ((hi << 8) | (((il & 3) ^ hi) << 4)));
    const bf16x8 qfb = *(const bf16x8*)(qbase + (((2 + hi) << 8) | (((il & 3) ^ (2 + hi)) << 4)));

    // ---- stage ALL K: wave w -> 16-row subtiles w*8..w*8+7 (R5 verbatim)
    #pragma unroll
    for (int st = 0; st < 8; ++st) {
        const float* r0 = kb + (size_t)(2 * dp) * 1024 + (w * 128 + st * 16) + 4 * jq;
        const float4 a = *(const float4*)(r0);
        const float4 b = *(const float4*)(r0 + 1024);
        unsigned* dst = (unsigned*)(smem + KOFF + (w * 8 + st) * 1024);
        dst[w0] = cvtpk(a.x, b.x);
        dst[w1] = cvtpk(a.y, b.y);
        dst[w2] = cvtpk(a.z, b.z);
        dst[w3] = cvtpk(a.w, b.w);
    }
    // ---- stage ALL V: thread row d = w*4+g, j-quad 4c, 16 tiles (R5 verbatim)
    {
        const int dv = w * 4 + g;
        #pragma unroll
        for (int tt = 0; tt < 16; ++tt) {
            const float4 vv = *(const float4*)(qb + (size_t)dv * 1024 + tt * 64 + 4 * c);
            const unsigned lo = cvtpk(vv.x, vv.y), hh = cvtpk(vv.z, vv.w);
            *(unsigned long long*)(smem + VOFF + tt * 4096 + dv * 128 +
                                   ((8 * c) ^ ((dv & 7) << 4))) =
                (unsigned long long)lo | ((unsigned long long)hh << 32);
        }
    }
    __syncthreads();   // K/V/Q resident; loop below barrier/LDS-write free

    f32x16 O, z16;
    #pragma unroll
    for (int r = 0; r < 16; ++r) { O[r] = 0.f; z16[r] = 0.f; }
    float lden = 0.f;  // softmax denom partial for q-row i = il

    #pragma unroll 1
    for (int t = 0; t < 16; ++t) {
        const int tile = (t + 2 * w) & 15;   // staggered per wave
        const unsigned char* vbase = smem + VOFF + tile * 4096 + il * 128;

        #pragma unroll
        for (int half = 0; half < 2; ++half) {
            // S = K * Q^T (M=j32, N=i32): lane holds col i=il,
            // rows j_loc = (r&3) + 8*(r>>2) + 4*hi (within this 32-row step)
            const unsigned char* kbs = smem + KOFF + (tile * 2 + half) * 2048 + qsel;
            const bf16x8 ka0 = *(const bf16x8*)(kbs + ((hi << 8) | (((il & 3) ^ hi) << 4)));
            const bf16x8 ka1 = *(const bf16x8*)(kbs + (((2 + hi) << 8) | (((il & 3) ^ (2 + hi)) << 4)));
            f32x16 S;
            __builtin_amdgcn_s_setprio(1);
            S = __builtin_amdgcn_mfma_f32_32x32x16_bf16(ka0, qfa, z16, 0, 0, 0);
            S = __builtin_amdgcn_mfma_f32_32x32x16_bf16(ka1, qfb, S, 0, 0, 0);
            __builtin_amdgcn_s_setprio(0);

            // P = exp2(S') = exp(sim); no max subtraction (|S'| bounded, fp32-safe)
            #pragma unroll
            for (int r = 0; r < 16; ++r) S[r] = expv(S[r]);
            const float t0 = (S[0] + S[1]) + (S[2] + S[3]);
            const float t1 = (S[4] + S[5]) + (S[6] + S[7]);
            const float t2 = (S[8] + S[9]) + (S[10] + S[11]);
            const float t3 = (S[12] + S[13]) + (S[14] + S[15]);
            lden += (t0 + t1) + (t2 + t3);

            // PV: A = P (M=i, k=j). After two SWAP32, [u0..u3] hold the lane's
            // k = 8*hi + e exactly (derivation matches HW-verified R5 pack).
            #pragma unroll
            for (int ks = 0; ks < 2; ++ks) {
                unsigned u0 = cvtpk(S[8 * ks + 0], S[8 * ks + 1]);
                unsigned u1 = cvtpk(S[8 * ks + 2], S[8 * ks + 3]);
                unsigned u2 = cvtpk(S[8 * ks + 4], S[8 * ks + 5]);
                unsigned u3 = cvtpk(S[8 * ks + 6], S[8 * ks + 7]);
                SWAP32(u0, u2); SWAP32(u1, u3);
                const u32x4 pw = {u0, u1, u2, u3};
                const bf16x8 pa = __builtin_bit_cast(bf16x8, pw);
                const unsigned col =
                    ((unsigned)(2 * (half * 32 + ks * 16 + 8 * hi))) ^ ((il & 7) << 4);
                const bf16x8 vbf = *(const bf16x8*)(vbase + col);
                __builtin_amdgcn_s_setprio(1);
                O = __builtin_amdgcn_mfma_f32_32x32x16_bf16(pa, vbf, O, 0, 0, 0);
                __builtin_amdgcn_s_setprio(0);
            }
        }
    }

    // ---- full denominators: other lane-half holds the complementary j-set
    lden += __shfl_xor(lden, 32);
    const float li = 1.0f / lden;   // denom of q-row i = il (valid in both halves)

    // ---- epilogue: bounce O through LDS (stride-33) so f_t loads coalesce
    __syncthreads();   // all waves done reading K/V/Q
    float* ow = (float*)smem + w * 1104;   // wave-own region in dead K space
    #pragma unroll
    for (int r = 0; r < 16; ++r) {
        const int ir = (r & 3) + 8 * (r >> 2) + 4 * hi;  // i-row of O[r]
        ow[ir * 33 + il] = O[r];                          // il = d column
    }
    // wave-local region: in-order LDS, no barrier needed
    const float* tvb = kb + (size_t)(q0 + w * 32) + il;
    float a0 = 0.f, a1 = 0.f;
    #pragma unroll
    for (int s = 0; s < 8; ++s) {
        const int d0 = 4 * s + hi, d1 = 4 * s + 2 + hi;
        const float e0 = ow[il * 33 + d0] * li - tvb[(size_t)d0 * 1024];
        const float e1 = ow[il * 33 + d1] * li - tvb[(size_t)d1 * 1024];
        a0 += e0 * e0; a1 += e1 * e1;
    }
    float acc = a0 + a1;
    #pragma unroll
    for (int off = 1; off < 64; off <<= 1) acc += __shfl_xor(acc, off);
    if (lane == 0) ((float*)(smem + REDX))[w] = acc;
    __syncthreads();
    if (tid == 0) {
        const float* lred = (const float*)(smem + REDX);
        float s = 0.f;
        #pragma unroll
        for (int i = 0; i < 8; ++i) s += lred[i];
        ws[bid] = s;                       // plain store: no init required
    }
    __threadfence();

    // ---- grid-wide sum: one launch, no memset, no atomics
    cg::this_grid().sync();
    if (bid == 0 && tid < 64) {
        float v = ws[tid] + ws[tid + 64] + ws[tid + 128] + ws[tid + 192];
        #pragma unroll
        for (int off = 1; off < 64; off <<= 1) v += __shfl_xor(v, off);
        if (tid == 0) out[0] = v * (1.0f / 2097152.0f);
    }
}

extern "C" void kernel_launch(void* const* d_in, const int* in_sizes, int n_in,
                              void* d_out, int out_size, void* d_ws, size_t ws_size,
                              hipStream_t stream) {
    const float* fs = (const float*)d_in[0];
    const float* ft = (const float*)d_in[1];
    float* out = (float*)d_out;
    float* ws  = (float*)d_ws;
    void* args[] = {(void*)&fs, (void*)&ft, (void*)&out, (void*)&ws};
    hipLaunchCooperativeKernel((const void*)attn_mse_kernel,
                               dim3(256), dim3(512), args, 0, stream);
}

// Round 13
// 27.762 us; speedup vs baseline: 3.7600x; 3.7600x over previous
//
#include <hip/hip_runtime.h>
#include <hip/hip_bf16.h>

// b=8, H=8, n=1024, d=32, fp32 in, scalar MSE loss out.
// Per pair p: Qt[d][n] = f_s[p*32768 + d*1024 + n]. sim = QK^T (unscaled),
// softmax over j, out = PV, loss = mean((out - f_t)^2).
//
// Block = 512 thr (8 waves), 32 q-rows/wave. Grid = 256 (1/CU, XCD swizzle).
// R9-verified staging/layouts + 32x32x16 MFMA loop. NEW vs R9:
//  - softmax denominator via ones-B MFMA (Oden = P*1), normalizing per-reg
//    in the epilogue with v_rcp -> removes ~15 VALU adds/half-step + shfl.
//  - t-loop unroll 2; exp via __builtin_amdgcn_exp2f when available.
// Normal launch + 4B memset (cooperative launch reverted: 3x slower, R12).

typedef __attribute__((ext_vector_type(4))) float f32x4;
typedef __attribute__((ext_vector_type(16))) float f32x16;
typedef __attribute__((ext_vector_type(8))) short bf16x8;
typedef __attribute__((ext_vector_type(4))) unsigned u32x4;

#define KOFF 0         // 64 subtiles x 1KB, R5 chunk layout (16 rows each)
#define VOFF 65536     // 16 tiles x [32 d][64 j] bf16, XOR-swizzled rows
#define QOFF 131072    // 8 waves x 2KB (two 16-row subtiles, R5 chunk layout)
#define REDX 40960     // final reduction scratch (K region, post-barrier)

__device__ __forceinline__ unsigned cvtpk(float a, float b) {
    unsigned r;  // r.lo = bf16(a), r.hi = bf16(b), RNE
    asm("v_cvt_pk_bf16_f32 %0, %1, %2" : "=v"(r) : "v"(a), "v"(b));
    return r;
}
#define SWAP32(a, b) asm("v_permlane32_swap_b32 %0, %1" : "+v"(a), "+v"(b))

__device__ __forceinline__ float expv(float x) {
#if __has_builtin(__builtin_amdgcn_exp2f)
    return __builtin_amdgcn_exp2f(x);
#else
    float r; asm("v_exp_f32 %0, %1" : "=v"(r) : "v"(x)); return r;
#endif
}
__device__ __forceinline__ float rcpv(float x) {
#if __has_builtin(__builtin_amdgcn_rcpf)
    return __builtin_amdgcn_rcpf(x);
#else
    float r; asm("v_rcp_f32 %0, %1" : "=v"(r) : "v"(x)); return r;
#endif
}

__global__ __launch_bounds__(512, 2)
void attn_mse_kernel(const float* __restrict__ fs, const float* __restrict__ ft,
                     float* __restrict__ out)
{
    __shared__ __align__(16) unsigned char smem[147456];

    const int tid  = threadIdx.x;
    const int lane = tid & 63;
    const int w    = tid >> 6;     // wave 0..7
    const int g    = lane >> 4;    // staging role 0..3
    const int c    = lane & 15;    // staging role 0..15
    const int il   = lane & 31;    // MFMA M/N lane index
    const int hi   = lane >> 5;    // MFMA k-half

    // XCD swizzle: 8 pairs x 4 q-blocks per XCD (bid%8) -> 2MB L2 set.
    const int bid  = blockIdx.x;
    const int pair = (bid & 7) * 8 + ((bid >> 3) & 7);
    const int q0   = (bid >> 6) * 256;

    const float* qb = fs + (size_t)pair * 32768;  // Q and V source
    const float* kb = ft + (size_t)pair * 32768;  // K source + loss target

    // R5 chunk-staging lane roles: word(dp, j) = p*64 + 16*(j>>2) + 4*((j&3)^p) + g
    // where dp = 4p+g (d-pair). (verified R5-R9)
    const int p_ = c >> 2, jq = c & 3;
    const int dp = 4 * p_ + g;
    const int w0 = p_ * 64 + 16 * jq + 4 * (0 ^ p_) + g;
    const int w1 = p_ * 64 + 16 * jq + 4 * (1 ^ p_) + g;
    const int w2 = p_ * 64 + 16 * jq + 4 * (2 ^ p_) + g;
    const int w3 = p_ * 64 + 16 * jq + 4 * (3 ^ p_) + g;

    // ---- stage Q (2 x 16-row subtiles per wave, pre-scaled by log2 e)
    {
        const float sc = 1.44269504f;
        #pragma unroll
        for (int st = 0; st < 2; ++st) {
            const float* r0 = qb + (size_t)(2 * dp) * 1024 + (q0 + w * 32 + st * 16) + 4 * jq;
            const float4 a = *(const float4*)(r0);
            const float4 b = *(const float4*)(r0 + 1024);
            unsigned* dst = (unsigned*)(smem + QOFF + w * 2048 + st * 1024);
            dst[w0] = cvtpk(a.x * sc, b.x * sc);
            dst[w1] = cvtpk(a.y * sc, b.y * sc);
            dst[w2] = cvtpk(a.z * sc, b.z * sc);
            dst[w3] = cvtpk(a.w * sc, b.w * sc);
        }
    }
    // 32-row fragment read from R5 layout: row il, chunk b:
    // byte = (il>>4)<<10 | b<<8 | ((il>>2)&3)<<6 | ((il&3)^b)<<4
    const unsigned qsel = ((unsigned)(il >> 4) << 10) | (((unsigned)(il >> 2) & 3) << 6);
    const unsigned char* qbase = smem + QOFF + w * 2048 + qsel;
    const bf16x8 qfa = *(const bf16x8*)(qbase + ((hi << 8) | (((il & 3) ^ hi) << 4)));
    const bf16x8 qfb = *(const bf16x8*)(qbase + (((2 + hi) << 8) | (((il & 3) ^ (2 + hi)) << 4)));

    // ---- stage ALL K: wave w -> 16-row subtiles w*8..w*8+7 (R5 verbatim)
    #pragma unroll
    for (int st = 0; st < 8; ++st) {
        const float* r0 = kb + (size_t)(2 * dp) * 1024 + (w * 128 + st * 16) + 4 * jq;
        const float4 a = *(const float4*)(r0);
        const float4 b = *(const float4*)(r0 + 1024);
        unsigned* dst = (unsigned*)(smem + KOFF + (w * 8 + st) * 1024);
        dst[w0] = cvtpk(a.x, b.x);
        dst[w1] = cvtpk(a.y, b.y);
        dst[w2] = cvtpk(a.z, b.z);
        dst[w3] = cvtpk(a.w, b.w);
    }
    // ---- stage ALL V: thread row d = w*4+g, j-quad 4c, 16 tiles (R5 verbatim)
    {
        const int dv = w * 4 + g;
        #pragma unroll
        for (int tt = 0; tt < 16; ++tt) {
            const float4 vv = *(const float4*)(qb + (size_t)dv * 1024 + tt * 64 + 4 * c);
            const unsigned lo = cvtpk(vv.x, vv.y), hh = cvtpk(vv.z, vv.w);
            *(unsigned long long*)(smem + VOFF + tt * 4096 + dv * 128 +
                                   ((8 * c) ^ ((dv & 7) << 4))) =
                (unsigned long long)lo | ((unsigned long long)hh << 32);
        }
    }
    __syncthreads();   // K/V/Q resident; loop below barrier/LDS-write free

    f32x16 O, Oden, z16;
    #pragma unroll
    for (int r = 0; r < 16; ++r) { O[r] = 0.f; Oden[r] = 0.f; z16[r] = 0.f; }
    // all-ones B fragment (layout-invariant): denom rows ride the matrix pipe
    const u32x4 onesw = {0x3F803F80u, 0x3F803F80u, 0x3F803F80u, 0x3F803F80u};
    const bf16x8 onesf = __builtin_bit_cast(bf16x8, onesw);

    #pragma unroll 2
    for (int t = 0; t < 16; ++t) {
        const int tile = (t + 2 * w) & 15;   // staggered per wave
        const unsigned char* vbase = smem + VOFF + tile * 4096 + il * 128;

        #pragma unroll
        for (int half = 0; half < 2; ++half) {
            // S = K * Q^T (M=j32, N=i32): lane holds col i=il,
            // rows j_loc = (r&3) + 8*(r>>2) + 4*hi (within this 32-row step)
            const unsigned char* kbs = smem + KOFF + (tile * 2 + half) * 2048 + qsel;
            const bf16x8 ka0 = *(const bf16x8*)(kbs + ((hi << 8) | (((il & 3) ^ hi) << 4)));
            const bf16x8 ka1 = *(const bf16x8*)(kbs + (((2 + hi) << 8) | (((il & 3) ^ (2 + hi)) << 4)));
            f32x16 S;
            __builtin_amdgcn_s_setprio(1);
            S = __builtin_amdgcn_mfma_f32_32x32x16_bf16(ka0, qfa, z16, 0, 0, 0);
            S = __builtin_amdgcn_mfma_f32_32x32x16_bf16(ka1, qfb, S, 0, 0, 0);
            __builtin_amdgcn_s_setprio(0);

            // P = exp2(S') = exp(sim); no max subtraction (|S'| bounded, fp32-safe)
            #pragma unroll
            for (int r = 0; r < 16; ++r) S[r] = expv(S[r]);

            // PV: A = P (M=i, k=j). After two SWAP32, [u0..u3] hold the lane's
            // k = 8*hi + e exactly (matches HW-verified R5 pack). Oden = P*1.
            #pragma unroll
            for (int ks = 0; ks < 2; ++ks) {
                unsigned u0 = cvtpk(S[8 * ks + 0], S[8 * ks + 1]);
                unsigned u1 = cvtpk(S[8 * ks + 2], S[8 * ks + 3]);
                unsigned u2 = cvtpk(S[8 * ks + 4], S[8 * ks + 5]);
                unsigned u3 = cvtpk(S[8 * ks + 6], S[8 * ks + 7]);
                SWAP32(u0, u2); SWAP32(u1, u3);
                const u32x4 pw = {u0, u1, u2, u3};
                const bf16x8 pa = __builtin_bit_cast(bf16x8, pw);
                const unsigned col =
                    ((unsigned)(2 * (half * 32 + ks * 16 + 8 * hi))) ^ ((il & 7) << 4);
                const bf16x8 vbf = *(const bf16x8*)(vbase + col);
                __builtin_amdgcn_s_setprio(1);
                O    = __builtin_amdgcn_mfma_f32_32x32x16_bf16(pa, vbf,   O,    0, 0, 0);
                Oden = __builtin_amdgcn_mfma_f32_32x32x16_bf16(pa, onesf, Oden, 0, 0, 0);
                __builtin_amdgcn_s_setprio(0);
            }
        }
    }

    // ---- epilogue: per-reg normalize (Oden[r] = denom of O[r]'s q-row),
    // bounce through LDS (stride-33) so f_t loads coalesce.
    __syncthreads();   // all waves done reading K/V/Q
    float* ow = (float*)smem + w * 1104;   // wave-own region in dead K space
    #pragma unroll
    for (int r = 0; r < 16; ++r) {
        const int ir = (r & 3) + 8 * (r >> 2) + 4 * hi;  // i-row of O[r]
        ow[ir * 33 + il] = O[r] * rcpv(Oden[r]);          // il = d column
    }
    // wave-local region: in-order LDS, no barrier needed
    const float* tvb = kb + (size_t)(q0 + w * 32) + il;
    float a0 = 0.f, a1 = 0.f;
    #pragma unroll
    for (int s = 0; s < 8; ++s) {
        const int d0 = 4 * s + hi, d1 = 4 * s + 2 + hi;
        const float e0 = ow[il * 33 + d0] - tvb[(size_t)d0 * 1024];
        const float e1 = ow[il * 33 + d1] - tvb[(size_t)d1 * 1024];
        a0 += e0 * e0; a1 += e1 * e1;
    }
    float acc = a0 + a1;
    #pragma unroll
    for (int off = 1; off < 64; off <<= 1) acc += __shfl_xor(acc, off);
    if (lane == 0) ((float*)(smem + REDX))[w] = acc;
    __syncthreads();
    if (tid == 0) {
        const float* lred = (const float*)(smem + REDX);
        float s = 0.f;
        #pragma unroll
        for (int i = 0; i < 8; ++i) s += lred[i];
        atomicAdd(out, s * (1.0f / 2097152.0f));
    }
}

extern "C" void kernel_launch(void* const* d_in, const int* in_sizes, int n_in,
                              void* d_out, int out_size, void* d_ws, size_t ws_size,
                              hipStream_t stream) {
    const float* fs = (const float*)d_in[0];
    const float* ft = (const float*)d_in[1];
    float* out = (float*)d_out;
    hipMemsetAsync(out, 0, sizeof(float), stream);
    attn_mse_kernel<<<dim3(256), dim3(512), 0, stream>>>(fs, ft, out);
}

// Round 14
// 26.527 us; speedup vs baseline: 3.9350x; 1.0465x over previous
//
#include <hip/hip_runtime.h>
#include <hip/hip_bf16.h>

// b=8, H=8, n=1024, d=32, fp32 in, scalar MSE loss out.
// Per pair p: Qt[d][n] = f_s[p*32768 + d*1024 + n]. sim = QK^T (unscaled),
// softmax over j, out = PV, loss = mean((out - f_t)^2).
//
// Block = 512 thr (8 waves), 32 q-rows/wave. Grid = 256 (1/CU, XCD swizzle).
// R9-verified staging/layouts + 32x32x16 MFMA loop (best: 27.5us). NEW:
// SINGLE dispatch -- no memset node. Blocks release-store partials to
// ws[bid]; device-scope counter at ws[256] (mod-256: works from any poison
// value, replay-safe); last block acquire-loads partials and OVERWRITES out.

typedef __attribute__((ext_vector_type(4))) float f32x4;
typedef __attribute__((ext_vector_type(16))) float f32x16;
typedef __attribute__((ext_vector_type(8))) short bf16x8;
typedef __attribute__((ext_vector_type(4))) unsigned u32x4;

#define KOFF 0         // 64 subtiles x 1KB, R5 chunk layout (16 rows each)
#define VOFF 65536     // 16 tiles x [32 d][64 j] bf16, XOR-swizzled rows
#define QOFF 131072    // 8 waves x 2KB (two 16-row subtiles, R5 chunk layout)
#define REDX 40960     // block reduction scratch (K region, post-barrier)

__device__ __forceinline__ unsigned cvtpk(float a, float b) {
    unsigned r;  // r.lo = bf16(a), r.hi = bf16(b), RNE
    asm("v_cvt_pk_bf16_f32 %0, %1, %2" : "=v"(r) : "v"(a), "v"(b));
    return r;
}
#define SWAP32(a, b) asm("v_permlane32_swap_b32 %0, %1" : "+v"(a), "+v"(b))

__device__ __forceinline__ float expv(float x) {
    float r;  // 2^x, native trans op
    asm("v_exp_f32 %0, %1" : "=v"(r) : "v"(x));
    return r;
}

__global__ __launch_bounds__(512, 2)
void attn_mse_kernel(const float* __restrict__ fs, const float* __restrict__ ft,
                     float* __restrict__ out, float* __restrict__ ws)
{
    __shared__ __align__(16) unsigned char smem[147456];

    const int tid  = threadIdx.x;
    const int lane = tid & 63;
    const int w    = tid >> 6;     // wave 0..7
    const int g    = lane >> 4;    // staging role 0..3
    const int c    = lane & 15;    // staging role 0..15
    const int il   = lane & 31;    // MFMA M/N lane index
    const int hi   = lane >> 5;    // MFMA k-half

    // XCD swizzle: 8 pairs x 4 q-blocks per XCD (bid%8) -> 2MB L2 set.
    const int bid  = blockIdx.x;
    const int pair = (bid & 7) * 8 + ((bid >> 3) & 7);
    const int q0   = (bid >> 6) * 256;

    const float* qb = fs + (size_t)pair * 32768;  // Q and V source
    const float* kb = ft + (size_t)pair * 32768;  // K source + loss target

    // R5 chunk-staging lane roles: word(dp, j) = p*64 + 16*(j>>2) + 4*((j&3)^p) + g
    // where dp = 4p+g (d-pair). (verified R5-R9)
    const int p_ = c >> 2, jq = c & 3;
    const int dp = 4 * p_ + g;
    const int w0 = p_ * 64 + 16 * jq + 4 * (0 ^ p_) + g;
    const int w1 = p_ * 64 + 16 * jq + 4 * (1 ^ p_) + g;
    const int w2 = p_ * 64 + 16 * jq + 4 * (2 ^ p_) + g;
    const int w3 = p_ * 64 + 16 * jq + 4 * (3 ^ p_) + g;

    // ---- stage Q (2 x 16-row subtiles per wave, pre-scaled by log2 e)
    {
        const float sc = 1.44269504f;
        #pragma unroll
        for (int st = 0; st < 2; ++st) {
            const float* r0 = qb + (size_t)(2 * dp) * 1024 + (q0 + w * 32 + st * 16) + 4 * jq;
            const float4 a = *(const float4*)(r0);
            const float4 b = *(const float4*)(r0 + 1024);
            unsigned* dst = (unsigned*)(smem + QOFF + w * 2048 + st * 1024);
            dst[w0] = cvtpk(a.x * sc, b.x * sc);
            dst[w1] = cvtpk(a.y * sc, b.y * sc);
            dst[w2] = cvtpk(a.z * sc, b.z * sc);
            dst[w3] = cvtpk(a.w * sc, b.w * sc);
        }
    }
    // 32-row fragment read from R5 layout: row il, chunk b:
    // byte = (il>>4)<<10 | b<<8 | ((il>>2)&3)<<6 | ((il&3)^b)<<4
    const unsigned qsel = ((unsigned)(il >> 4) << 10) | (((unsigned)(il >> 2) & 3) << 6);
    const unsigned char* qbase = smem + QOFF + w * 2048 + qsel;
    const bf16x8 qfa = *(const bf16x8*)(qbase + ((hi << 8) | (((il & 3) ^ hi) << 4)));
    const bf16x8 qfb = *(const bf16x8*)(qbase + (((2 + hi) << 8) | (((il & 3) ^ (2 + hi)) << 4)));

    // ---- stage ALL K: wave w -> 16-row subtiles w*8..w*8+7 (R5 verbatim)
    #pragma unroll
    for (int st = 0; st < 8; ++st) {
        const float* r0 = kb + (size_t)(2 * dp) * 1024 + (w * 128 + st * 16) + 4 * jq;
        const float4 a = *(const float4*)(r0);
        const float4 b = *(const float4*)(r0 + 1024);
        unsigned* dst = (unsigned*)(smem + KOFF + (w * 8 + st) * 1024);
        dst[w0] = cvtpk(a.x, b.x);
        dst[w1] = cvtpk(a.y, b.y);
        dst[w2] = cvtpk(a.z, b.z);
        dst[w3] = cvtpk(a.w, b.w);
    }
    // ---- stage ALL V: thread row d = w*4+g, j-quad 4c, 16 tiles (R5 verbatim)
    {
        const int dv = w * 4 + g;
        #pragma unroll
        for (int tt = 0; tt < 16; ++tt) {
            const float4 vv = *(const float4*)(qb + (size_t)dv * 1024 + tt * 64 + 4 * c);
            const unsigned lo = cvtpk(vv.x, vv.y), hh = cvtpk(vv.z, vv.w);
            *(unsigned long long*)(smem + VOFF + tt * 4096 + dv * 128 +
                                   ((8 * c) ^ ((dv & 7) << 4))) =
                (unsigned long long)lo | ((unsigned long long)hh << 32);
        }
    }
    __syncthreads();   // K/V/Q resident; loop below barrier/LDS-write free

    f32x16 O, z16;
    #pragma unroll
    for (int r = 0; r < 16; ++r) { O[r] = 0.f; z16[r] = 0.f; }
    float lden = 0.f;  // softmax denom partial for q-row i = il

    #pragma unroll 1
    for (int t = 0; t < 16; ++t) {
        const int tile = (t + 2 * w) & 15;   // staggered per wave
        const unsigned char* vbase = smem + VOFF + tile * 4096 + il * 128;

        #pragma unroll
        for (int half = 0; half < 2; ++half) {
            // S = K * Q^T (M=j32, N=i32): lane holds col i=il,
            // rows j_loc = (r&3) + 8*(r>>2) + 4*hi (within this 32-row step)
            const unsigned char* kbs = smem + KOFF + (tile * 2 + half) * 2048 + qsel;
            const bf16x8 ka0 = *(const bf16x8*)(kbs + ((hi << 8) | (((il & 3) ^ hi) << 4)));
            const bf16x8 ka1 = *(const bf16x8*)(kbs + (((2 + hi) << 8) | (((il & 3) ^ (2 + hi)) << 4)));
            f32x16 S;
            __builtin_amdgcn_s_setprio(1);
            S = __builtin_amdgcn_mfma_f32_32x32x16_bf16(ka0, qfa, z16, 0, 0, 0);
            S = __builtin_amdgcn_mfma_f32_32x32x16_bf16(ka1, qfb, S, 0, 0, 0);
            __builtin_amdgcn_s_setprio(0);

            // P = exp2(S') = exp(sim); no max subtraction (|S'| bounded, fp32-safe)
            #pragma unroll
            for (int r = 0; r < 16; ++r) S[r] = expv(S[r]);
            const float t0 = (S[0] + S[1]) + (S[2] + S[3]);
            const float t1 = (S[4] + S[5]) + (S[6] + S[7]);
            const float t2 = (S[8] + S[9]) + (S[10] + S[11]);
            const float t3 = (S[12] + S[13]) + (S[14] + S[15]);
            lden += (t0 + t1) + (t2 + t3);

            // PV: A = P (M=i, k=j). After two SWAP32, [u0..u3] hold the lane's
            // k = 8*hi + e exactly (derivation matches HW-verified R5 pack).
            #pragma unroll
            for (int ks = 0; ks < 2; ++ks) {
                unsigned u0 = cvtpk(S[8 * ks + 0], S[8 * ks + 1]);
                unsigned u1 = cvtpk(S[8 * ks + 2], S[8 * ks + 3]);
                unsigned u2 = cvtpk(S[8 * ks + 4], S[8 * ks + 5]);
                unsigned u3 = cvtpk(S[8 * ks + 6], S[8 * ks + 7]);
                SWAP32(u0, u2); SWAP32(u1, u3);
                const u32x4 pw = {u0, u1, u2, u3};
                const bf16x8 pa = __builtin_bit_cast(bf16x8, pw);
                const unsigned col =
                    ((unsigned)(2 * (half * 32 + ks * 16 + 8 * hi))) ^ ((il & 7) << 4);
                const bf16x8 vbf = *(const bf16x8*)(vbase + col);
                __builtin_amdgcn_s_setprio(1);
                O = __builtin_amdgcn_mfma_f32_32x32x16_bf16(pa, vbf, O, 0, 0, 0);
                __builtin_amdgcn_s_setprio(0);
            }
        }
    }

    // ---- full denominators: other lane-half holds the complementary j-set
    lden += __shfl_xor(lden, 32);
    const float li = 1.0f / lden;   // denom of q-row i = il (valid in both halves)

    // ---- epilogue: bounce O through LDS (stride-33) so f_t loads coalesce
    __syncthreads();   // all waves done reading K/V/Q
    float* ow = (float*)smem + w * 1104;   // wave-own region in dead K space
    #pragma unroll
    for (int r = 0; r < 16; ++r) {
        const int ir = (r & 3) + 8 * (r >> 2) + 4 * hi;  // i-row of O[r]
        ow[ir * 33 + il] = O[r];                          // il = d column
    }
    // wave-local region: in-order LDS, no barrier needed
    const float* tvb = kb + (size_t)(q0 + w * 32) + il;
    float a0 = 0.f, a1 = 0.f;
    #pragma unroll
    for (int s = 0; s < 8; ++s) {
        const int d0 = 4 * s + hi, d1 = 4 * s + 2 + hi;
        const float e0 = ow[il * 33 + d0] * li - tvb[(size_t)d0 * 1024];
        const float e1 = ow[il * 33 + d1] * li - tvb[(size_t)d1 * 1024];
        a0 += e0 * e0; a1 += e1 * e1;
    }
    float acc = a0 + a1;
    #pragma unroll
    for (int off = 1; off < 64; off <<= 1) acc += __shfl_xor(acc, off);
    if (lane == 0) ((float*)(smem + REDX))[w] = acc;
    __syncthreads();

    // ---- single-dispatch grid finalize: partial -> ws[bid]; mod-256 counter
    // at ws[256] (replay-safe from any initial value); last arrival reduces.
    if (w == 0) {
        if (lane == 0) {
            const float* lred = (const float*)(smem + REDX);
            float s = 0.f;
            #pragma unroll
            for (int i = 0; i < 8; ++i) s += lred[i];
            __hip_atomic_store(&ws[bid], s, __ATOMIC_RELEASE,
                               __HIP_MEMORY_SCOPE_AGENT);
        }
        unsigned old = 0;
        if (lane == 0)
            old = __hip_atomic_fetch_add((unsigned*)(ws + 256), 1u,
                                         __ATOMIC_ACQ_REL, __HIP_MEMORY_SCOPE_AGENT);
        old = __shfl(old, 0);
        if ((old & 255u) == 255u) {   // last of this replay's 256 blocks
            float v = 0.f;
            #pragma unroll
            for (int i = 0; i < 4; ++i)
                v += __hip_atomic_load(&ws[lane + 64 * i], __ATOMIC_ACQUIRE,
                                       __HIP_MEMORY_SCOPE_AGENT);
            #pragma unroll
            for (int off = 1; off < 64; off <<= 1) v += __shfl_xor(v, off);
            if (lane == 0) out[0] = v * (1.0f / 2097152.0f);
        }
    }
}

extern "C" void kernel_launch(void* const* d_in, const int* in_sizes, int n_in,
                              void* d_out, int out_size, void* d_ws, size_t ws_size,
                              hipStream_t stream) {
    const float* fs = (const float*)d_in[0];
    const float* ft = (const float*)d_in[1];
    float* out = (float*)d_out;
    float* ws  = (float*)d_ws;
    attn_mse_kernel<<<dim3(256), dim3(512), 0, stream>>>(fs, ft, out, ws);
}